// Round 7
// baseline (87.539 us; speedup 1.0000x reference)
//
#include <hip/hip_runtime.h>

#define EPS 1e-4f

constexpr int B  = 8;
constexpr int C  = 128;
constexpr int Tt = 9;
constexpr int T  = 8;
constexpr int H  = 64;
constexpr int W  = 64;
constexpr int HW = H * W;          // 4096
constexpr int HM = 256;
constexpr int WM = 256;
constexpr int HWM = HM * WM;       // 65536

typedef __attribute__((ext_vector_type(4))) float f32x4;

// ws layout (float offsets). Every cell written before read each replay.
constexpr int WS_RV    = 0;                        // rv floats  B*T*HW = 262144
constexpr int WS_GSP   = WS_RV + B * T * HW;       // gs partials [b][t][c] = 8192
constexpr int WS_VSP   = WS_GSP + B * T * C;       // vs partials [b][t][q] = 256
constexpr int WS_VMB_F = WS_VSP + B * T * 4;       // vm bytes B*T*HW bytes
// total ≈ 270k floats + 256 KB bytes ≈ 1.3 MB

__device__ __forceinline__ const f32x4& ld4(const float* p) {
  return *reinterpret_cast<const f32x4*>(p);
}
__device__ __forceinline__ void st4(float* p, f32x4 v) {
  *reinterpret_cast<f32x4*>(p) = v;
}

// --- antialiased bilinear downsample 256 -> 64 (scale 1/4), one output pixel.
// jax.image.resize 'bilinear' antialias=True: sample = 4o+1.5, taps 4o-2..4o+5,
// unnormalized weights {1,3,5,7,7,5,3,1}, per-dim renormalized over valid taps.
__device__ __forceinline__ float resample_px(const float* __restrict__ src,
                                             int y, int x) {
  const float wt[8] = {1.f, 3.f, 5.f, 7.f, 7.f, 5.f, 3.f, 1.f};
  int by = 4 * y - 2, bx = 4 * x - 2;
  float wx[8];
  float nx = 0.f;
  #pragma unroll
  for (int d = 0; d < 8; ++d) {
    int xx = bx + d;
    float w = (xx >= 0 && xx < WM) ? wt[d] : 0.f;
    wx[d] = w;
    nx += w;
  }
  float ny = 0.f;
  float sum = 0.f;
  #pragma unroll
  for (int dy = 0; dy < 8; ++dy) {
    int yy = by + dy;
    if (yy < 0 || yy >= HM) continue;
    ny += wt[dy];
    const float* row = src + yy * WM;
    float rowsum = 0.f;
    #pragma unroll
    for (int dx = 0; dx < 8; ++dx) {
      int xx = bx + dx;
      xx = xx < 0 ? 0 : (xx >= WM ? WM - 1 : xx);  // clamp addr; weight 0 if OOB
      rowsum += wx[dx] * row[xx];
    }
    sum += wt[dy] * rowsum;
  }
  return sum / (ny * nx);
}

// Kernel A: per-(b,t,quarter) block computes rv floats + vm bytes + vs count.
// tv is recomputed per (b,t) (cheap) and never stored.
// grid = B*T*4 = 256 blocks x 256 threads.
__global__ __launch_bounds__(256) void mask_kernel(
    const float* __restrict__ tvmap, const float* __restrict__ rvmaps,
    float* __restrict__ ws) {
  int bid = blockIdx.x;
  int q = bid & 3, bt = bid >> 2;
  int b = bt >> 3;
  int tid = threadIdx.x;

  const float* tsrc = tvmap + (size_t)b * HWM;
  const float* rsrc = rvmaps + (size_t)bt * HWM;
  float* rvf = ws + WS_RV + bt * HW;
  unsigned char* vmb = (unsigned char*)(ws + WS_VMB_F) + bt * HW;

  int cnt = 0;
  #pragma unroll
  for (int k = 0; k < 4; ++k) {
    int px = q * 1024 + k * 256 + tid;
    int y = px >> 6, x = px & 63;
    float tv = resample_px(tsrc, y, x);
    float rv = resample_px(rsrc, y, x);
    bool rb = rv > 0.5f;
    rvf[px] = rb ? 1.f : 0.f;
    unsigned char v = (tv > 0.5f && rb) ? 1 : 0;
    vmb[px] = v;
    cnt += v;
  }

  float fc = (float)cnt;
  #pragma unroll
  for (int m = 32; m > 0; m >>= 1) fc += __shfl_xor(fc, m);
  __shared__ float red[4];
  int lane = tid & 63, wave = tid >> 6;
  if (lane == 0) red[wave] = fc;
  __syncthreads();
  if (tid == 0)
    ws[WS_VSP + bt * 4 + q] = red[0] + red[1] + red[2] + red[3];
}

// Kernel B: one 16 KB rf-plane per block. grid = T*B*C = 8192 blocks (t-major
// so the tf plane is L3-hot for t>=1), 256 threads, 4 f32x4 chunks/thread.
__global__ __launch_bounds__(256) void gs_kernel(
    const float* __restrict__ values, float* __restrict__ ws) {
  int bid = blockIdx.x;            // t*1024 + b*128 + c
  int t = bid >> 10;
  int bc = bid & 1023;
  int b = bc >> 7, c = bc & 127;
  int tid = threadIdx.x;

  const float* tf = values + (size_t)(b * C + c) * Tt * HW;
  const float* rf = tf + (size_t)(t + 1) * HW;
  const uchar4* vm = (const uchar4*)
      ((const unsigned char*)(ws + WS_VMB_F) + (b * T + t) * HW);

  float partial = 0.f;
  #pragma unroll
  for (int k = 0; k < 4; ++k) {
    int i = k * 256 + tid;
    f32x4 a = ld4(tf + 4 * i);
    f32x4 r = ld4(rf + 4 * i);
    uchar4 u = vm[i];
    partial += (u.x ? a[0] * r[0] : 0.f) + (u.y ? a[1] * r[1] : 0.f) +
               (u.z ? a[2] * r[2] : 0.f) + (u.w ? a[3] * r[3] : 0.f);
  }

  #pragma unroll
  for (int m = 32; m > 0; m >>= 1) partial += __shfl_xor(partial, m);
  __shared__ float red[4];
  int lane = tid & 63, wave = tid >> 6;
  if (lane == 0) red[wave] = partial;
  __syncthreads();
  if (tid == 0)
    ws[WS_GSP + (b * T + t) * C + c] = red[0] + red[1] + red[2] + red[3];
}

// Kernel C: finalize gs (redundant, tiny) + per-px softmax + t_feat copy +
// c_out + c_mask. 512 blocks = b(8) x cc(16) x hq(4); values reads L3-warm.
__global__ __launch_bounds__(256) void out_kernel(
    const float* __restrict__ values, const float* __restrict__ ws,
    float* __restrict__ out) {
  int bid = blockIdx.x;
  int hq = bid & 3, cc = (bid >> 2) & 15, b = bid >> 6;
  int tid = threadIdx.x;
  int px = hq * 1024 + tid * 4;

  __shared__ float gsf_sh[T];
  if (tid < 64) {
    int t = tid >> 3, part = tid & 7;
    float s = 0.f;
    #pragma unroll
    for (int k = 0; k < 16; ++k)
      s += ws[WS_GSP + (b * T + t) * C + part * 16 + k];
    #pragma unroll
    for (int m = 1; m < 8; m <<= 1) s += __shfl_xor(s, m);
    if (part == 0) {
      float vs = 0.f;
      #pragma unroll
      for (int qq = 0; qq < 4; ++qq) vs += ws[WS_VSP + (b * T + t) * 4 + qq];
      bool zero = vs < EPS;           // vs is an exact integer-valued count
      float g = zero ? 0.f : s;
      vs += zero ? 1.f : 0.f;
      gsf_sh[t] = g / vs / (float)C;
    }
  }
  __syncthreads();

  float gsf[T];
  #pragma unroll
  for (int t = 0; t < T; ++t) gsf[t] = gsf_sh[t];

  f32x4 rv[T], cm[T];
  #pragma unroll
  for (int t = 0; t < T; ++t)
    rv[t] = ld4(ws + WS_RV + (b * T + t) * HW + px);

  // masked_vec = gsf*rv (zeros where rv=0 participate in the max)
  f32x4 mx = gsf[0] * rv[0];
  #pragma unroll
  for (int t = 1; t < T; ++t) {
    #pragma unroll
    for (int j = 0; j < 4; ++j) mx[j] = fmaxf(mx[j], gsf[t] * rv[t][j]);
  }
  f32x4 s = {0.f, 0.f, 0.f, 0.f};
  #pragma unroll
  for (int t = 0; t < T; ++t) {
    #pragma unroll
    for (int j = 0; j < 4; ++j)
      cm[t][j] = expf(gsf[t] * rv[t][j] - mx[j]) * rv[t][j];
    s += cm[t];
  }
  #pragma unroll
  for (int j = 0; j < 4; ++j) {
    s[j] += (s[j] < EPS) ? 1.f : 0.f;
    s[j] = 1.f / s[j];
  }
  f32x4 csum = {0.f, 0.f, 0.f, 0.f};
  #pragma unroll
  for (int t = 0; t < T; ++t) {
    cm[t] *= s;
    csum += cm[t];
  }

  if (cc == 0) {
    f32x4 cmask;
    #pragma unroll
    for (int j = 0; j < 4; ++j) cmask[j] = 1.f - csum[j];
    st4(out + ((size_t)b * 257 + 256) * HW + px, cmask);
    st4(out + (size_t)B * 257 * HW + (size_t)b * HW + px, cmask);
  }

  const float* vb = values + (size_t)(b * C + cc * 8) * Tt * HW;
  #pragma unroll 2
  for (int c = 0; c < 8; ++c) {
    const float* vc = vb + (size_t)c * Tt * HW;
    f32x4 tf = ld4(vc + px);
    st4(out + ((size_t)b * 257 + cc * 8 + c) * HW + px, tf);  // t_feat copy
    f32x4 acc = {0.f, 0.f, 0.f, 0.f};
    #pragma unroll
    for (int t = 0; t < T; ++t) {
      f32x4 rf = ld4(vc + (t + 1) * HW + px);
      acc += rf * cm[t];
    }
    st4(out + ((size_t)b * 257 + 128 + cc * 8 + c) * HW + px, acc);
  }
}

extern "C" void kernel_launch(void* const* d_in, const int* in_sizes, int n_in,
                              void* d_out, int out_size, void* d_ws, size_t ws_size,
                              hipStream_t stream) {
  const float* values = (const float*)d_in[0];
  const float* tvmap  = (const float*)d_in[1];
  const float* rvmaps = (const float*)d_in[2];
  float* out = (float*)d_out;
  float* ws  = (float*)d_ws;

  hipLaunchKernelGGL(mask_kernel, dim3(B * T * 4), dim3(256), 0, stream,
                     tvmap, rvmaps, ws);
  hipLaunchKernelGGL(gs_kernel, dim3(T * B * C), dim3(256), 0, stream,
                     values, ws);
  hipLaunchKernelGGL(out_kernel, dim3(512), dim3(256), 0, stream,
                     values, ws, out);
}

// Round 8
// 81.106 us; speedup vs baseline: 1.0793x; 1.0793x over previous
//
#include <hip/hip_runtime.h>

#define EPS 1e-4f

constexpr int B  = 8;
constexpr int C  = 128;
constexpr int Tt = 9;
constexpr int T  = 8;
constexpr int H  = 64;
constexpr int W  = 64;
constexpr int HW = H * W;          // 4096
constexpr int HM = 256;
constexpr int WM = 256;
constexpr int HWM = HM * WM;       // 65536

typedef __attribute__((ext_vector_type(4))) float f32x4;

// ws layout. Every cell written before read each replay — no zero-init needed.
constexpr int WS_GSP   = 0;                    // gs partials [b][t][c] = 8192 f
constexpr int WS_VSP   = WS_GSP + B * T * C;   // vs partials [bt][q8]  = 512 f
constexpr int WS_END_F = WS_VSP + B * T * 8;
// byte regions (offsets in bytes from ws + WS_END_F*4)
constexpr int WSB_RV = 0;                      // rv bytes  B*T*HW = 256 KB
constexpr int WSB_VM = WSB_RV + B * T * HW;    // vm bytes  B*T*HW = 256 KB

__device__ __forceinline__ const f32x4& ld4(const float* p) {
  return *reinterpret_cast<const f32x4*>(p);
}
__device__ __forceinline__ void st4(float* p, f32x4 v) {
  *reinterpret_cast<f32x4*>(p) = v;
}

// --- antialiased bilinear downsample 256 -> 64 (scale 1/4), one output pixel.
// jax.image.resize 'bilinear' antialias=True: sample = 4o+1.5, taps 4o-2..4o+5,
// unnormalized weights {1,3,5,7,7,5,3,1}, per-dim renormalized over valid taps.
__device__ __forceinline__ float resample_px(const float* __restrict__ src,
                                             int y, int x) {
  const float wt[8] = {1.f, 3.f, 5.f, 7.f, 7.f, 5.f, 3.f, 1.f};
  int by = 4 * y - 2, bx = 4 * x - 2;
  float wx[8];
  float nx = 0.f;
  #pragma unroll
  for (int d = 0; d < 8; ++d) {
    int xx = bx + d;
    float w = (xx >= 0 && xx < WM) ? wt[d] : 0.f;
    wx[d] = w;
    nx += w;
  }
  float ny = 0.f;
  float sum = 0.f;
  #pragma unroll
  for (int dy = 0; dy < 8; ++dy) {
    int yy = by + dy;
    if (yy < 0 || yy >= HM) continue;
    ny += wt[dy];
    const float* row = src + yy * WM;
    float rowsum = 0.f;
    #pragma unroll
    for (int dx = 0; dx < 8; ++dx) {
      int xx = bx + dx;
      xx = xx < 0 ? 0 : (xx >= WM ? WM - 1 : xx);  // clamp addr; weight 0 if OOB
      rowsum += wx[dx] * row[xx];
    }
    sum += wt[dy] * rowsum;
  }
  return sum / (ny * nx);
}

// Kernel A: rv bytes + vm bytes + vs counts. grid = bt(64) x q(8) = 512 blocks.
__global__ __launch_bounds__(256) void mask_kernel(
    const float* __restrict__ tvmap, const float* __restrict__ rvmaps,
    float* __restrict__ ws) {
  int bid = blockIdx.x;
  int q = bid & 7, bt = bid >> 3;
  int b = bt >> 3;
  int tid = threadIdx.x;

  unsigned char* wsb = (unsigned char*)(ws + WS_END_F);
  const float* tsrc = tvmap + (size_t)b * HWM;
  const float* rsrc = rvmaps + (size_t)bt * HWM;
  unsigned char* rvb = wsb + WSB_RV + bt * HW;
  unsigned char* vmb = wsb + WSB_VM + bt * HW;

  int cnt = 0;
  #pragma unroll
  for (int k = 0; k < 2; ++k) {
    int px = q * 512 + k * 256 + tid;
    int y = px >> 6, x = px & 63;
    float tv = resample_px(tsrc, y, x);
    float rv = resample_px(rsrc, y, x);
    unsigned char rb = rv > 0.5f ? 1 : 0;
    unsigned char v = (tv > 0.5f) ? rb : 0;
    rvb[px] = rb;
    vmb[px] = v;
    cnt += v;
  }

  float fc = (float)cnt;
  #pragma unroll
  for (int m = 32; m > 0; m >>= 1) fc += __shfl_xor(fc, m);
  __shared__ float red[4];
  int lane = tid & 63, wave = tid >> 6;
  if (lane == 0) red[wave] = fc;
  __syncthreads();
  if (tid == 0)
    ws[WS_VSP + bt * 8 + q] = red[0] + red[1] + red[2] + red[3];
}

// Kernel B: ONE WAVE OWNS ONE rf-PLANE. 8192 waves = 2048 blocks x 256 thr
// (8 blocks/CU -> 100% occupancy ceiling). No LDS, no __syncthreads, no
// block tail — wave-level shuffle reduce only. t-major so tf planes are
// cache-hot for t>=1.
__global__ __launch_bounds__(256) void gs_kernel(
    const float* __restrict__ values, float* __restrict__ ws) {
  int wid = blockIdx.x * 4 + (threadIdx.x >> 6);   // 0..8191 = t*1024 + b*128 + c
  int lane = threadIdx.x & 63;
  int t = wid >> 10;
  int bc = wid & 1023;                              // b*128 + c
  int b = bc >> 7, c = bc & 127;

  const float* tf = values + (size_t)bc * Tt * HW;
  const float* rf = tf + (size_t)(t + 1) * HW;
  const uchar4* vm = (const uchar4*)((const unsigned char*)(ws + WS_END_F) +
                                     WSB_VM + (b * T + t) * HW);

  float acc = 0.f;
  #pragma unroll 4
  for (int k = 0; k < 16; ++k) {
    int f = k * 256 + lane * 4;
    f32x4 a = ld4(tf + f);
    f32x4 r = ld4(rf + f);
    uchar4 u = vm[k * 64 + lane];
    acc += (u.x ? a[0] * r[0] : 0.f) + (u.y ? a[1] * r[1] : 0.f) +
           (u.z ? a[2] * r[2] : 0.f) + (u.w ? a[3] * r[3] : 0.f);
  }

  #pragma unroll
  for (int m = 32; m > 0; m >>= 1) acc += __shfl_xor(acc, m);
  if (lane == 0) ws[WS_GSP + (b * T + t) * C + c] = acc;
}

// Kernel C: finalize gs (redundant, tiny) + per-px softmax (rv from L2-hot
// bytes) + t_feat copy + c_out + c_mask. grid = b(8) x cc(32) x hq(4) = 1024
// blocks, 4 channels per block.
__global__ __launch_bounds__(256) void out_kernel(
    const float* __restrict__ values, const float* __restrict__ ws,
    float* __restrict__ out) {
  int bid = blockIdx.x;
  int hq = bid & 3, cc = (bid >> 2) & 31, b = bid >> 7;
  int tid = threadIdx.x;
  int px = hq * 1024 + tid * 4;

  __shared__ float gsf_sh[T];
  if (tid < 64) {
    int t = tid >> 3, part = tid & 7;
    float s = 0.f;
    #pragma unroll
    for (int k = 0; k < 16; ++k)
      s += ws[WS_GSP + (b * T + t) * C + part * 16 + k];
    #pragma unroll
    for (int m = 1; m < 8; m <<= 1) s += __shfl_xor(s, m);
    if (part == 0) {
      float vs = 0.f;
      #pragma unroll
      for (int qq = 0; qq < 8; ++qq) vs += ws[WS_VSP + (b * T + t) * 8 + qq];
      bool zero = vs < EPS;           // vs is an exact integer-valued count
      float g = zero ? 0.f : s;
      vs += zero ? 1.f : 0.f;
      gsf_sh[t] = g / vs / (float)C;
    }
  }
  __syncthreads();

  float gsf[T];
  #pragma unroll
  for (int t = 0; t < T; ++t) gsf[t] = gsf_sh[t];

  const unsigned char* rvb =
      (const unsigned char*)(ws + WS_END_F) + WSB_RV + b * T * HW;
  uchar4 ub[T];
  #pragma unroll
  for (int t = 0; t < T; ++t)
    ub[t] = *reinterpret_cast<const uchar4*>(rvb + t * HW + px);

  // masked_vec = gsf*rv; zeros (rv=0) participate in the max
  f32x4 mx;
  #pragma unroll
  for (int j = 0; j < 4; ++j) mx[j] = 0.f;   // exp term is exact below; mx from masked values
  #pragma unroll
  for (int t = 0; t < T; ++t) {
    mx[0] = fmaxf(mx[0], ub[t].x ? gsf[t] : 0.f);
    mx[1] = fmaxf(mx[1], ub[t].y ? gsf[t] : 0.f);
    mx[2] = fmaxf(mx[2], ub[t].z ? gsf[t] : 0.f);
    mx[3] = fmaxf(mx[3], ub[t].w ? gsf[t] : 0.f);
  }
  // NOTE: reference max starts from masked_vec values themselves (all 8 of
  // them, including zeros) — identical to starting at 0 only if some entry
  // is >= 0; masked_vec entries are {0 or gsf}, and 0 is always a member
  // when any rv=0... but if ALL rv=1 and all gsf<0, ref max = max(gsf)<0.
  // Handle exactly: recompute mx properly.
  #pragma unroll
  for (int j = 0; j < 4; ++j) {
    float m0 = (j == 0 ? (ub[0].x ? gsf[0] : 0.f)
               : j == 1 ? (ub[0].y ? gsf[0] : 0.f)
               : j == 2 ? (ub[0].z ? gsf[0] : 0.f)
                        : (ub[0].w ? gsf[0] : 0.f));
    mx[j] = m0;
  }
  #pragma unroll
  for (int t = 1; t < T; ++t) {
    mx[0] = fmaxf(mx[0], ub[t].x ? gsf[t] : 0.f);
    mx[1] = fmaxf(mx[1], ub[t].y ? gsf[t] : 0.f);
    mx[2] = fmaxf(mx[2], ub[t].z ? gsf[t] : 0.f);
    mx[3] = fmaxf(mx[3], ub[t].w ? gsf[t] : 0.f);
  }

  f32x4 cm[T];
  f32x4 s = {0.f, 0.f, 0.f, 0.f};
  #pragma unroll
  for (int t = 0; t < T; ++t) {
    cm[t][0] = ub[t].x ? __expf(gsf[t] - mx[0]) : 0.f;
    cm[t][1] = ub[t].y ? __expf(gsf[t] - mx[1]) : 0.f;
    cm[t][2] = ub[t].z ? __expf(gsf[t] - mx[2]) : 0.f;
    cm[t][3] = ub[t].w ? __expf(gsf[t] - mx[3]) : 0.f;
    s += cm[t];
  }
  #pragma unroll
  for (int j = 0; j < 4; ++j) {
    s[j] += (s[j] < EPS) ? 1.f : 0.f;
    s[j] = 1.f / s[j];
  }
  f32x4 csum = {0.f, 0.f, 0.f, 0.f};
  #pragma unroll
  for (int t = 0; t < T; ++t) {
    cm[t] *= s;
    csum += cm[t];
  }

  if (cc == 0) {
    f32x4 cmask;
    #pragma unroll
    for (int j = 0; j < 4; ++j) cmask[j] = 1.f - csum[j];
    st4(out + ((size_t)b * 257 + 256) * HW + px, cmask);
    st4(out + (size_t)B * 257 * HW + (size_t)b * HW + px, cmask);
  }

  const float* vb = values + (size_t)(b * C + cc * 4) * Tt * HW;
  #pragma unroll
  for (int c = 0; c < 4; ++c) {
    const float* vc = vb + (size_t)c * Tt * HW;
    f32x4 tf = ld4(vc + px);
    st4(out + ((size_t)b * 257 + cc * 4 + c) * HW + px, tf);  // t_feat copy
    f32x4 acc = {0.f, 0.f, 0.f, 0.f};
    #pragma unroll
    for (int t = 0; t < T; ++t) {
      f32x4 rf = ld4(vc + (t + 1) * HW + px);
      acc += rf * cm[t];
    }
    st4(out + ((size_t)b * 257 + 128 + cc * 4 + c) * HW + px, acc);
  }
}

extern "C" void kernel_launch(void* const* d_in, const int* in_sizes, int n_in,
                              void* d_out, int out_size, void* d_ws, size_t ws_size,
                              hipStream_t stream) {
  const float* values = (const float*)d_in[0];
  const float* tvmap  = (const float*)d_in[1];
  const float* rvmaps = (const float*)d_in[2];
  float* out = (float*)d_out;
  float* ws  = (float*)d_ws;

  hipLaunchKernelGGL(mask_kernel, dim3(512), dim3(256), 0, stream,
                     tvmap, rvmaps, ws);
  hipLaunchKernelGGL(gs_kernel, dim3(2048), dim3(256), 0, stream,
                     values, ws);
  hipLaunchKernelGGL(out_kernel, dim3(1024), dim3(256), 0, stream,
                     values, ws, out);
}